// Round 7
// baseline (354.388 us; speedup 1.0000x reference)
//
#include <hip/hip_runtime.h>
#include <stdint.h>

// K-Planes hash-grid encoder, MI355X.
// Cost model (r2-r6): ~4.1-4.6 us per MILLION divergent vector-memory
// requests, locality-independent -> minimize request count.
//  K0 packexpand: pts2[plane][pt] + DENSE (lvl,cx,cy) tables for lvl 0-10
//     (divergent hash reads paid once: 1.04M; all staging after = coalesced).
//  K1 hi: levels 11-15 (15 groups), contiguous per-XCD chunk ranges
//     (exact balance, quasi-resident), float4 even-u0 corner pairing,
//     4 pts/thread MLP.  23.6M divergent reqs.
//  K2 s810: levels 8-10 row-striped 51KB LDS (52 stripes/plane), linear
//     dense staging, predicated scan.  Removes 14.1M divergent reqs.
//  K3 low: levels 0-7 per-level/stripe regions, C=32, dense staging.
//  K4 combine: 3-plane product + LDS transpose.
// Fallbacks: Plan B (r2 3-pass), mono.

#define NPTS   524288u
#define TSIZE  524288u
#define TMASK  0x7FFFFu
#define PRIME1 2654435761u

// d_out scratch layout (float2 elements); combine overwrites at the end.
#define PTS2_OFF     0u
#define DHI_OFF      1572864u      // 3*NPTS
#define DHI_PSTRIDE  298043u       // 45369 + 87025 + 165649
#define DLO_OFF      2466993u      // DHI_OFF + 3*DHI_PSTRIDE
#define DLO_PSTRIDE  49930u        // sum E lvl0-7
#define EXP_TOTAL    1043919u      // 3*(49930+298043)
#define EXP_PER_PL   347973u

__constant__ float c_res[16] = {
    16.f, 22.f, 30.f, 42.f, 58.f, 80.f, 111.f, 153.f,
    212.f, 294.f, 406.f, 561.f, 775.f, 1072.f, 1481.f, 2047.f
};
__constant__ uint32_t c_Rlo[8]   = {17, 23, 31, 43, 59, 81, 112, 154};
__constant__ uint32_t c_offlo[8] = {0, 289, 818, 1779, 3628, 7109, 13670, 26214};
__constant__ uint32_t c_Rhi[3]   = {213, 295, 407};
__constant__ uint32_t c_offhi[3] = {0, 45369, 132394};

// ---------------- K0: pack pts2 + expand dense tables -----------------------
__global__ __launch_bounds__(256) void kplane_packexpand(
    const float* __restrict__ pts,
    const float2* __restrict__ tab,
    float2* __restrict__ scr)         // d_out as float2 scratch
{
    const uint32_t b = blockIdx.x, t = threadIdx.x;
    if (b < 2048u) {
        const uint32_t pt = b * 256u + t;
        const float x = pts[pt * 3u + 0u];
        const float y = pts[pt * 3u + 1u];
        const float z = pts[pt * 3u + 2u];
        scr[PTS2_OFF +             pt] = make_float2(x, y);
        scr[PTS2_OFF + NPTS      + pt] = make_float2(x, z);
        scr[PTS2_OFF + 2u * NPTS + pt] = make_float2(y, z);
        return;
    }
    const uint32_t idx = (b - 2048u) * 256u + t;
    if (idx >= EXP_TOTAL) return;
    const uint32_t plane = idx / EXP_PER_PL;
    const uint32_t i     = idx - plane * EXP_PER_PL;
    if (i < DLO_PSTRIDE) {
        uint32_t lvl = 7u;
        while (i < c_offlo[lvl]) lvl--;
        const uint32_t R     = c_Rlo[lvl];
        const uint32_t local = i - c_offlo[lvl];
        const uint32_t cx = local / R, cy = local - cx * R;
        scr[DLO_OFF + plane * DLO_PSTRIDE + i] =
            tab[(plane * 16u + lvl) * TSIZE + ((cx ^ (cy * PRIME1)) & TMASK)];
    } else {
        const uint32_t j  = i - DLO_PSTRIDE;
        const uint32_t li = (j < 45369u) ? 0u : (j < 132394u ? 1u : 2u);
        const uint32_t R     = c_Rhi[li];
        const uint32_t local = j - c_offhi[li];
        const uint32_t cx = local / R, cy = local - cx * R;
        scr[DHI_OFF + plane * DHI_PSTRIDE + j] =
            tab[(plane * 16u + (8u + li)) * TSIZE +
                ((cx ^ (cy * PRIME1)) & TMASK)];
    }
}

// ---------------- K1: levels 11-15, balanced contiguous XCD ranges ----------
__global__ __launch_bounds__(256) void kplane_hi(
    const float2* __restrict__ scr,   // pts2 at PTS2_OFF
    const float2* __restrict__ tab,
    float2* __restrict__ ws)
{
    const uint32_t b   = blockIdx.x;         // 7680 = 15 groups x 512 chunks
    const uint32_t xcd = b & 7u;
    const uint32_t j   = b >> 3;             // 0..959
    const uint32_t ci  = xcd * 960u + j;     // contiguous sweep per XCD
    const uint32_t g   = ci >> 9;            // 0..14
    const uint32_t cig = ci & 511u;
    const uint32_t lvl   = 11u + g / 3u;
    const uint32_t plane = g - (g / 3u) * 3u;
    const uint32_t gabs  = plane * 16u + lvl;
    const float    res   = c_res[lvl];
    const uint32_t base  = gabs * TSIZE;
    const float4* __restrict__ tab4 = (const float4*)tab;
    const uint32_t b4    = gabs * (TSIZE / 2u);
    const float2* __restrict__ pp = scr + PTS2_OFF + (size_t)plane * NPTS;
    const uint32_t pt0   = cig * 1024u + threadIdx.x;

    float4 P0[4], P1[4];
    float2 Q0[4], Q1[4];
    float  r0[4], r1[4];
    uint32_t sel0[4], sel1[4], oddm[4];

#pragma unroll
    for (int k = 0; k < 4; ++k) {            // issue all loads first
        const uint32_t pt = pt0 + (uint32_t)k * 256u;
        const float2 c2 = pp[pt];
        const float s0 = c2.x * res;
        const float s1 = c2.y * res;
        const float f0 = floorf(s0);
        const float f1 = floorf(s1);
        r0[k] = s0 - f0;                     // exact f32 match to reference
        r1[k] = s1 - f1;
        const uint32_t u0  = (uint32_t)f0;
        const uint32_t hy0 = (uint32_t)f1 * PRIME1;
        const uint32_t hy1 = hy0 + PRIME1;
        const uint32_t i00 = ( u0        ^ hy0) & TMASK;
        const uint32_t i01 = ( u0        ^ hy1) & TMASK;
        const uint32_t i10 = ((u0 + 1u)  ^ hy0) & TMASK;
        const uint32_t i11 = ((u0 + 1u)  ^ hy1) & TMASK;
        sel0[k] = i00 & 1u;
        sel1[k] = i01 & 1u;
        oddm[k] = u0 & 1u;
        P0[k] = tab4[b4 + (i00 >> 1)];       // covers t00 (+t10 if u0 even)
        P1[k] = tab4[b4 + (i01 >> 1)];       // covers t01 (+t11 if u0 even)
        Q0[k] = make_float2(0.f, 0.f);
        Q1[k] = make_float2(0.f, 0.f);
        if (oddm[k]) {                       // exec-masked, ~50% lanes
            Q0[k] = tab[base + i10];
            Q1[k] = tab[base + i11];
        }
    }
#pragma unroll
    for (int k = 0; k < 4; ++k) {
        const uint32_t pt = pt0 + (uint32_t)k * 256u;
        const float2 lo0 = make_float2(P0[k].x, P0[k].y);
        const float2 hi0 = make_float2(P0[k].z, P0[k].w);
        const float2 lo1 = make_float2(P1[k].x, P1[k].y);
        const float2 hi1 = make_float2(P1[k].z, P1[k].w);
        const float2 t00 = sel0[k] ? hi0 : lo0;
        const float2 t01 = sel1[k] ? hi1 : lo1;
        const float2 t10 = oddm[k] ? Q0[k] : (sel0[k] ? lo0 : hi0);
        const float2 t11 = oddm[k] ? Q1[k] : (sel1[k] ? lo1 : hi1);
        const float w00 = (1.f - r0[k]) * (1.f - r1[k]);
        const float w01 = (1.f - r0[k]) * r1[k];
        const float w10 = r0[k] * (1.f - r1[k]);
        const float w11 = r0[k] * r1[k];
        ws[(size_t)gabs * NPTS + pt] = make_float2(
            w00 * t00.x + w01 * t01.x + w10 * t10.x + w11 * t11.x,
            w00 * t00.y + w01 * t01.y + w10 * t10.y + w11 * t11.y);
    }
}

// ---------------- K2: levels 8-10, row-striped LDS from dense ---------------
__global__ __launch_bounds__(512) void kplane_s810(
    const float2* __restrict__ scr,   // pts2 + dense
    float2* __restrict__ ws)
{
    __shared__ float2 sm[6390];              // 51.1 KB max (30 rows x 213)
    const uint32_t b     = blockIdx.x;       // 156 stripe-sets x 16 chunks
    const uint32_t sp    = b >> 4;
    const uint32_t chunk = b & 15u;
    const uint32_t plane = sp / 52u;
    const uint32_t s     = sp - plane * 52u;
    uint32_t lvl, R, span, lo, offp;
    if (s < 8u)       { lvl = 8u;  R = 213u; span = 29u; lo = s * 29u;         offp = 0u; }
    else if (s < 23u) { lvl = 9u;  R = 295u; span = 20u; lo = (s - 8u) * 20u;  offp = 45369u; }
    else              { lvl = 10u; R = 407u; span = 14u; lo = (s - 23u) * 14u; offp = 132394u; }
    const uint32_t nrows = (span + 1u < R - lo) ? span + 1u : R - lo;
    const uint32_t E     = nrows * R;
    const uint32_t dbase = DHI_OFF + plane * DHI_PSTRIDE + offp + lo * R;
    const uint32_t t     = threadIdx.x;

    for (uint32_t i = t; i < E; i += 512u)   // linear coalesced staging
        sm[i] = scr[dbase + i];
    __syncthreads();

    const float res = c_res[lvl];
    const float2* __restrict__ pp = scr + PTS2_OFF + (size_t)plane * NPTS;
    float2* __restrict__ wsg = ws + (size_t)(plane * 16u + lvl) * NPTS;
    const uint32_t pt0 = chunk * 32768u + t;
    const uint32_t hiX = lo + span;

#pragma unroll 4
    for (uint32_t k = 0; k < 64u; ++k) {
        const uint32_t pt = pt0 + k * 512u;
        const float2 c2 = pp[pt];
        const float s0 = c2.x * res;
        const float s1 = c2.y * res;
        const float f0 = floorf(s0);
        const float f1 = floorf(s1);
        const uint32_t u0 = (uint32_t)f0;
        if (u0 >= lo && u0 < hiX) {
            const float r0 = s0 - f0;
            const float r1 = s1 - f1;
            const uint32_t ci = (u0 - lo) * R + (uint32_t)f1;
            const float2 q00 = sm[ci];
            const float2 q01 = sm[ci + 1u];
            const float2 q10 = sm[ci + R];
            const float2 q11 = sm[ci + R + 1u];
            const float w00 = (1.f - r0) * (1.f - r1);
            const float w01 = (1.f - r0) * r1;
            const float w10 = r0 * (1.f - r1);
            const float w11 = r0 * r1;
            wsg[pt] = make_float2(
                w00 * q00.x + w01 * q01.x + w10 * q10.x + w11 * q11.x,
                w00 * q00.y + w01 * q01.y + w10 * q10.y + w11 * q11.y);
        }
    }
}

// ---------------- K3: levels 0-7, per-level/stripe regions from dense -------
__global__ __launch_bounds__(512) void kplane_low(
    const float2* __restrict__ scr,
    float2* __restrict__ ws)
{
    __shared__ float2 sm[6561];              // 52.5 KB max (lvl 5 full)
    const uint32_t b     = blockIdx.x;       // 36 regions x 32 chunks
    const uint32_t rgp   = b >> 5;
    const uint32_t chunk = b & 31u;
    const uint32_t plane = rgp / 12u;
    const uint32_t rg    = rgp - plane * 12u;
    uint32_t lvl, lo, span;
    if (rg < 6u)      { lvl = rg;  lo = 0u;            span = c_Rlo[rg]; }
    else if (rg < 8u) { lvl = 6u;  lo = (rg - 6u) * 56u; span = 56u; }
    else              { lvl = 7u;  lo = (rg - 8u) * 39u; span = 39u; }
    const uint32_t R     = c_Rlo[lvl];
    const uint32_t nrows = (span + 1u < R - lo) ? span + 1u : R - lo;
    const uint32_t E     = nrows * R;
    const uint32_t dbase = DLO_OFF + plane * DLO_PSTRIDE + c_offlo[lvl] + lo * R;
    const uint32_t t     = threadIdx.x;

    for (uint32_t i = t; i < E; i += 512u)
        sm[i] = scr[dbase + i];
    __syncthreads();

    const float res = c_res[lvl];
    const float2* __restrict__ pp = scr + PTS2_OFF + (size_t)plane * NPTS;
    float2* __restrict__ wsg = ws + (size_t)(plane * 16u + lvl) * NPTS;
    const uint32_t pt0 = chunk * 16384u + t;
    const uint32_t hiX = lo + span;

#pragma unroll 4
    for (uint32_t k = 0; k < 32u; ++k) {
        const uint32_t pt = pt0 + k * 512u;
        const float2 c2 = pp[pt];
        const float s0 = c2.x * res;
        const float s1 = c2.y * res;
        const float f0 = floorf(s0);
        const float f1 = floorf(s1);
        const uint32_t u0 = (uint32_t)f0;
        if (u0 >= lo && u0 < hiX) {
            const float r0 = s0 - f0;
            const float r1 = s1 - f1;
            const uint32_t ci = (u0 - lo) * R + (uint32_t)f1;
            const float2 q00 = sm[ci];
            const float2 q01 = sm[ci + 1u];
            const float2 q10 = sm[ci + R];
            const float2 q11 = sm[ci + R + 1u];
            const float w00 = (1.f - r0) * (1.f - r1);
            const float w01 = (1.f - r0) * r1;
            const float w10 = r0 * (1.f - r1);
            const float w11 = r0 * r1;
            wsg[pt] = make_float2(
                w00 * q00.x + w01 * q01.x + w10 * q10.x + w11 * q11.x,
                w00 * q00.y + w01 * q01.y + w10 * q10.y + w11 * q11.y);
        }
    }
}

// ---------------- K4: combine 3 planes, transpose via LDS -------------------
__global__ __launch_bounds__(256) void kplane_combine(
    const float2* __restrict__ ws,    // (48, NPTS)
    float2* __restrict__ out)         // (NPTS, 16)
{
    __shared__ float2 tile[16][65];
    const uint32_t pt0 = blockIdx.x * 64u;
    const uint32_t t   = threadIdx.x;
    const uint32_t lr  = t >> 6;
    const uint32_t ptl = t & 63u;

#pragma unroll
    for (int k = 0; k < 4; ++k) {
        const uint32_t lvl = (uint32_t)k * 4u + lr;
        const float2 a = ws[( 0u + lvl) * NPTS + pt0 + ptl];
        const float2 b = ws[(16u + lvl) * NPTS + pt0 + ptl];
        const float2 c = ws[(32u + lvl) * NPTS + pt0 + ptl];
        tile[lvl][ptl] = make_float2(a.x * b.x * c.x, a.y * b.y * c.y);
    }
    __syncthreads();
#pragma unroll
    for (int k = 0; k < 4; ++k) {
        const uint32_t e      = t + (uint32_t)k * 256u;
        const uint32_t out_lv = e & 15u;
        const uint32_t out_pt = e >> 4;
        out[(pt0 + out_pt) * 16u + out_lv] = tile[out_lv][out_pt];
    }
}

// ---------------- Plan B fallback: r2 3-pass + transpose --------------------
template <int P, bool FIRST>
__global__ __launch_bounds__(256) void kplane_pass(
    const float* __restrict__ pts,
    const float2* __restrict__ tab,
    float2* __restrict__ ws)
{
    const uint32_t b     = blockIdx.x;
    const uint32_t xcd   = b & 7u;
    const uint32_t s     = b >> 3;
    const uint32_t gi    = s >> 11;
    const uint32_t chunk = s & 2047u;
    const uint32_t lvl   = gi * 8u + xcd;
    const uint32_t pt    = chunk * 256u + threadIdx.x;

    constexpr int c0 = (P == 2) ? 1 : 0;
    constexpr int c1 = (P == 0) ? 1 : 2;

    const float a0  = pts[pt * 3u + c0];
    const float a1  = pts[pt * 3u + c1];
    const float res = c_res[lvl];

    const float s0 = a0 * res;
    const float s1 = a1 * res;
    const float f0 = floorf(s0);
    const float f1 = floorf(s1);
    const float r0 = s0 - f0;
    const float r1 = s1 - f1;
    const uint32_t u0 = (uint32_t)f0;
    const uint32_t hy0  = (uint32_t)f1 * PRIME1;
    const uint32_t hy1  = hy0 + PRIME1;
    const uint32_t base = ((uint32_t)P * 16u + lvl) * TSIZE;

    const float2 t00 = tab[base + (( u0       ^ hy0) & TMASK)];
    const float2 t01 = tab[base + (( u0       ^ hy1) & TMASK)];
    const float2 t10 = tab[base + (((u0 + 1u) ^ hy0) & TMASK)];
    const float2 t11 = tab[base + (((u0 + 1u) ^ hy1) & TMASK)];

    const float w00 = (1.f - r0) * (1.f - r1);
    const float w01 = (1.f - r0) * r1;
    const float w10 = r0 * (1.f - r1);
    const float w11 = r0 * r1;

    const float e0 = w00 * t00.x + w01 * t01.x + w10 * t10.x + w11 * t11.x;
    const float e1 = w00 * t00.y + w01 * t01.y + w10 * t10.y + w11 * t11.y;

    const uint32_t widx = lvl * NPTS + pt;
    if (FIRST) {
        ws[widx] = make_float2(e0, e1);
    } else {
        const float2 prev = ws[widx];
        ws[widx] = make_float2(prev.x * e0, prev.y * e1);
    }
}

__global__ __launch_bounds__(256) void kplane_transpose(
    const float2* __restrict__ ws, float2* __restrict__ out)
{
    const uint32_t tid = blockIdx.x * 256u + threadIdx.x;
    const uint32_t lvl = tid & 15u;
    const uint32_t pt  = tid >> 4;
    out[tid] = ws[lvl * NPTS + pt];
}

__global__ __launch_bounds__(256) void kplane_mono(
    const float* __restrict__ pts,
    const float2* __restrict__ tab,
    float2* __restrict__ out)
{
    const uint32_t tid = blockIdx.x * 256u + threadIdx.x;
    const uint32_t pt  = tid >> 4;
    const uint32_t lvl = tid & 15u;
    const float x = pts[pt * 3u + 0u];
    const float y = pts[pt * 3u + 1u];
    const float z = pts[pt * 3u + 2u];
    const float res = c_res[lvl];
    const float a0[3] = {x, x, y};
    const float a1[3] = {y, z, z};
    float p0 = 1.f, p1 = 1.f;
#pragma unroll
    for (int pl = 0; pl < 3; ++pl) {
        const float s0 = a0[pl] * res;
        const float s1 = a1[pl] * res;
        const float f0 = floorf(s0);
        const float f1 = floorf(s1);
        const float r0 = s0 - f0;
        const float r1 = s1 - f1;
        const uint32_t u0 = (uint32_t)f0;
        const uint32_t hy0 = (uint32_t)f1 * PRIME1;
        const uint32_t hy1 = hy0 + PRIME1;
        const uint32_t base = ((uint32_t)pl * 16u + lvl) * TSIZE;
        const float2 t00 = tab[base + (( u0       ^ hy0) & TMASK)];
        const float2 t01 = tab[base + (( u0       ^ hy1) & TMASK)];
        const float2 t10 = tab[base + (((u0 + 1u) ^ hy0) & TMASK)];
        const float2 t11 = tab[base + (((u0 + 1u) ^ hy1) & TMASK)];
        const float w00 = (1.f - r0) * (1.f - r1);
        const float w01 = (1.f - r0) * r1;
        const float w10 = r0 * (1.f - r1);
        const float w11 = r0 * r1;
        p0 *= w00 * t00.x + w01 * t01.x + w10 * t10.x + w11 * t11.x;
        p1 *= w00 * t00.y + w01 * t01.y + w10 * t10.y + w11 * t11.y;
    }
    out[pt * 16u + lvl] = make_float2(p0, p1);
}

extern "C" void kernel_launch(void* const* d_in, const int* in_sizes, int n_in,
                              void* d_out, int out_size, void* d_ws, size_t ws_size,
                              hipStream_t stream) {
    const float*  pts = (const float*)d_in[0];
    const float2* tab = (const float2*)d_in[1];
    float2*       out = (float2*)d_out;

    const size_t wsA = (size_t)48 * NPTS * sizeof(float2);   // 201.3 MB
    const size_t wsB = (size_t)16 * NPTS * sizeof(float2);   //  67.1 MB
    dim3 block256(256u), block512(512u);

    if (ws_size >= wsA) {
        float2* ws  = (float2*)d_ws;
        float2* scr = (float2*)d_out;   // 21 MB scratch, dead before combine
        hipLaunchKernelGGL(kplane_packexpand, dim3(2048u + 4078u), block256,
                           0, stream, pts, tab, scr);
        hipLaunchKernelGGL(kplane_hi, dim3(7680u), block256, 0, stream,
                           scr, tab, ws);
        hipLaunchKernelGGL(kplane_s810, dim3(2496u), block512, 0, stream,
                           scr, ws);
        hipLaunchKernelGGL(kplane_low, dim3(1152u), block512, 0, stream,
                           scr, ws);
        hipLaunchKernelGGL(kplane_combine, dim3(NPTS / 64u), block256, 0,
                           stream, ws, out);
    } else if (ws_size >= wsB) {
        float2* ws = (float2*)d_ws;
        dim3 grid(16u * (NPTS / 256u));
        hipLaunchKernelGGL((kplane_pass<0, true >), grid, block256, 0, stream, pts, tab, ws);
        hipLaunchKernelGGL((kplane_pass<1, false>), grid, block256, 0, stream, pts, tab, ws);
        hipLaunchKernelGGL((kplane_pass<2, false>), grid, block256, 0, stream, pts, tab, ws);
        dim3 tgrid((NPTS * 16u) / 256u);
        hipLaunchKernelGGL(kplane_transpose, tgrid, block256, 0, stream, ws, out);
    } else {
        dim3 grid((NPTS * 16u) / 256u);
        hipLaunchKernelGGL(kplane_mono, grid, block256, 0, stream, pts, tab, out);
    }
}

// Round 8
// 264.640 us; speedup vs baseline: 1.3391x; 1.3391x over previous
//
#include <hip/hip_runtime.h>
#include <stdint.h>

// K-Planes hash-grid encoder, MI355X.
// Cost model (r2-r7): ~4.3 us per MILLION divergent vector-memory requests,
// locality-independent. Predicated stripe-scan costs scale with stripe count
// (r7 lesson: 52 stripes/plane = 135 us of ~3%-efficient waves). Levels 8-15
// direct gather = 37.7M reqs = 173 us floor (r6-measured).
// Round-8 structure:
//  K0 packexpand: pts2[plane][pt] (coalesced coord reads) + DENSE levels 0-7
//     (150K divergent hash reads paid once -> all staging coalesced).
//  K1 fused: ONE kernel, two grid regions (256-thr blocks, 29 KB LDS cap
//     -> 5 blocks/CU, ~20 waves, >= r6 hi occupancy):
//       [0,1440):  low/mid scan-sets (l0-3 packed, l4, l5 x2 stripes,
//                  l6 x4, l7 x7), coalesced dense staging, predicated scan.
//                  VALU/LDS-pipe work, dispatched FIRST to overlap...
//       [1440,13728): hi = r6's proven levels 8-15 direct gather (TA-pipe),
//                  XCD-L2 residency via b&7, float4 even-u0 corner pairing.
//  K2 combine: 3-plane product + LDS transpose (proven, 34 us).
// Fallbacks: Plan B (r2 3-pass, 353 us), mono.

#define NPTS   524288u
#define TSIZE  524288u
#define TMASK  0x7FFFFu
#define PRIME1 2654435761u

// scr (= d_out scratch, float2 elements; combine overwrites at the end)
#define PTS2_OFF     0u
#define DEXP_OFF     1572864u     // 3*NPTS
#define DEXP_PSTRIDE 49930u       // sum E, levels 0-7 (dense, full levels)
#define DEXP_TOTAL   149790u     // 3*49930

__constant__ float c_res[16] = {
    16.f, 22.f, 30.f, 42.f, 58.f, 80.f, 111.f, 153.f,
    212.f, 294.f, 406.f, 561.f, 775.f, 1072.f, 1481.f, 2047.f
};
__constant__ uint32_t c_Rlo[8]   = {17, 23, 31, 43, 59, 81, 112, 154};
__constant__ uint32_t c_offlo[8] = {0, 289, 818, 1779, 3628, 7109, 13670, 26214};

// fused low/mid scan-sets s=0..14 (s0 = levels 0-3 packed, special-cased)
__constant__ uint8_t c_slvl[15] = {0, 4, 5, 5, 6, 6, 6, 6, 7, 7, 7, 7, 7, 7, 7};
__constant__ uint8_t c_slo [15] = {0, 0, 0, 40, 0, 28, 56, 84, 0, 22, 44, 66, 88, 110, 132};
__constant__ uint8_t c_shi [15] = {0, 59, 40, 81, 28, 56, 84, 112, 22, 44, 66, 88, 110, 132, 154};

// ---------------- K0: pack pts2 + expand dense levels 0-7 -------------------
__global__ __launch_bounds__(256) void kplane_packexpand(
    const float* __restrict__ pts,
    const float2* __restrict__ tab,
    float2* __restrict__ scr)
{
    const uint32_t b = blockIdx.x, t = threadIdx.x;
    if (b < 2048u) {
        const uint32_t pt = b * 256u + t;
        const float x = pts[pt * 3u + 0u];
        const float y = pts[pt * 3u + 1u];
        const float z = pts[pt * 3u + 2u];
        scr[PTS2_OFF +             pt] = make_float2(x, y);   // plane 0
        scr[PTS2_OFF + NPTS      + pt] = make_float2(x, z);   // plane 1
        scr[PTS2_OFF + 2u * NPTS + pt] = make_float2(y, z);   // plane 2
        return;
    }
    const uint32_t idx = (b - 2048u) * 256u + t;
    if (idx >= DEXP_TOTAL) return;
    const uint32_t plane = idx / DEXP_PSTRIDE;
    const uint32_t i     = idx - plane * DEXP_PSTRIDE;
    uint32_t lvl = 7u;
    while (i < c_offlo[lvl]) lvl--;
    const uint32_t R     = c_Rlo[lvl];
    const uint32_t local = i - c_offlo[lvl];
    const uint32_t cx = local / R, cy = local - cx * R;
    scr[DEXP_OFF + plane * DEXP_PSTRIDE + i] =
        tab[(plane * 16u + lvl) * TSIZE + ((cx ^ (cy * PRIME1)) & TMASK)];
}

// ---------------- K1: fused low/mid (LDS) + hi (direct gather) --------------
__global__ __launch_bounds__(256) void kplane_fused(
    const float2* __restrict__ scr,   // pts2 + dense
    const float2* __restrict__ tab,
    float2* __restrict__ ws)          // (48, NPTS)
{
    __shared__ float2 sm[3628];              // 29 KB cap -> 5 blocks/CU
    const uint32_t b = blockIdx.x;
    const uint32_t t = threadIdx.x;

    if (b < 1440u) {
        // ---- low/mid region: 45 scan-sets x 32 chunks ----
        const uint32_t set   = b >> 5;
        const uint32_t chunk = b & 31u;
        const uint32_t plane = set / 15u;
        const uint32_t s     = set - plane * 15u;
        const float2* __restrict__ pp = scr + PTS2_OFF + (size_t)plane * NPTS;
        const uint32_t pt0 = chunk * 16384u + t;

        if (s == 0u) {
            // levels 0-3 packed (3628 entries), unconditional scan
            const uint32_t dbase = DEXP_OFF + plane * DEXP_PSTRIDE;
            for (uint32_t i = t; i < 3628u; i += 256u) sm[i] = scr[dbase + i];
            __syncthreads();
#pragma unroll 2
            for (uint32_t k = 0; k < 64u; ++k) {
                const uint32_t pt = pt0 + k * 256u;
                const float2 c2 = pp[pt];
#pragma unroll
                for (int l = 0; l < 4; ++l) {
                    const uint32_t R   = c_Rlo[l];
                    const uint32_t off = c_offlo[l];
                    const float res = c_res[l];
                    const float s0 = c2.x * res;
                    const float s1 = c2.y * res;
                    const float f0 = floorf(s0);
                    const float f1 = floorf(s1);
                    const float r0 = s0 - f0;    // exact f32 match to reference
                    const float r1 = s1 - f1;
                    const uint32_t ci = off + (uint32_t)f0 * R + (uint32_t)f1;
                    const float2 q00 = sm[ci];
                    const float2 q01 = sm[ci + 1u];
                    const float2 q10 = sm[ci + R];
                    const float2 q11 = sm[ci + R + 1u];
                    const float w00 = (1.f - r0) * (1.f - r1);
                    const float w01 = (1.f - r0) * r1;
                    const float w10 = r0 * (1.f - r1);
                    const float w11 = r0 * r1;
                    ws[(size_t)(plane * 16u + (uint32_t)l) * NPTS + pt] =
                        make_float2(
                        w00 * q00.x + w01 * q01.x + w10 * q10.x + w11 * q11.x,
                        w00 * q00.y + w01 * q01.y + w10 * q10.y + w11 * q11.y);
                }
            }
        } else {
            // single level, stripe [lo,hiX), <=29 KB
            const uint32_t lvl = c_slvl[s];
            const uint32_t R   = c_Rlo[lvl];
            const uint32_t lo  = c_slo[s];
            const uint32_t hiX = c_shi[s];
            const uint32_t capr = (hiX < R) ? hiX : R - 1u;
            const uint32_t E    = (capr - lo + 1u) * R;
            const uint32_t dbase =
                DEXP_OFF + plane * DEXP_PSTRIDE + c_offlo[lvl] + lo * R;
            for (uint32_t i = t; i < E; i += 256u) sm[i] = scr[dbase + i];
            __syncthreads();

            const float res = c_res[lvl];
            float2* __restrict__ wsg = ws + (size_t)(plane * 16u + lvl) * NPTS;
#pragma unroll 4
            for (uint32_t k = 0; k < 64u; ++k) {
                const uint32_t pt = pt0 + k * 256u;
                const float2 c2 = pp[pt];
                const float s0 = c2.x * res;
                const float s1 = c2.y * res;
                const float f0 = floorf(s0);
                const float f1 = floorf(s1);
                const uint32_t u0 = (uint32_t)f0;
                if (u0 >= lo && u0 < hiX) {
                    const float r0 = s0 - f0;
                    const float r1 = s1 - f1;
                    const uint32_t ci = (u0 - lo) * R + (uint32_t)f1;
                    const float2 q00 = sm[ci];
                    const float2 q01 = sm[ci + 1u];
                    const float2 q10 = sm[ci + R];
                    const float2 q11 = sm[ci + R + 1u];
                    const float w00 = (1.f - r0) * (1.f - r1);
                    const float w01 = (1.f - r0) * r1;
                    const float w10 = r0 * (1.f - r1);
                    const float w11 = r0 * r1;
                    wsg[pt] = make_float2(
                        w00 * q00.x + w01 * q01.x + w10 * q10.x + w11 * q11.x,
                        w00 * q00.y + w01 * q01.y + w10 * q10.y + w11 * q11.y);
                }
            }
        }
        return;
    }

    // ---- hi region: levels 8-15 direct gather (r6-proven) ----
    const uint32_t hb    = b - 1440u;        // 1440 % 8 == 0: b&7 preserved
    const uint32_t xcd   = hb & 7u;
    const uint32_t sjk   = hb >> 3;
    const uint32_t phase = sjk >> 9;         // 0..2
    const uint32_t chunk = sjk & 511u;       // 512 chunks x 1024 pts
    const uint32_t plane = phase;
    const uint32_t lvl   = 8u + ((xcd + 3u * phase) & 7u);
    const uint32_t gabs  = plane * 16u + lvl;
    const float    res   = c_res[lvl];
    const uint32_t base  = gabs * TSIZE;
    const float4* __restrict__ tab4 = (const float4*)tab;
    const uint32_t b4    = gabs * (TSIZE / 2u);
    const float2* __restrict__ pp = scr + PTS2_OFF + (size_t)plane * NPTS;
    const uint32_t pt0   = chunk * 1024u + t;

    float4 P0[4], P1[4];
    float2 Q0[4], Q1[4];
    float  r0[4], r1[4];
    uint32_t sel0[4], sel1[4], oddm[4];

#pragma unroll
    for (int k = 0; k < 4; ++k) {            // issue all loads first
        const uint32_t pt = pt0 + (uint32_t)k * 256u;
        const float2 c2 = pp[pt];
        const float s0 = c2.x * res;
        const float s1 = c2.y * res;
        const float f0 = floorf(s0);
        const float f1 = floorf(s1);
        r0[k] = s0 - f0;                     // exact f32 match to reference
        r1[k] = s1 - f1;
        const uint32_t u0  = (uint32_t)f0;
        const uint32_t hy0 = (uint32_t)f1 * PRIME1;
        const uint32_t hy1 = hy0 + PRIME1;
        const uint32_t i00 = ( u0        ^ hy0) & TMASK;
        const uint32_t i01 = ( u0        ^ hy1) & TMASK;
        const uint32_t i10 = ((u0 + 1u)  ^ hy0) & TMASK;
        const uint32_t i11 = ((u0 + 1u)  ^ hy1) & TMASK;
        sel0[k] = i00 & 1u;
        sel1[k] = i01 & 1u;
        oddm[k] = u0 & 1u;
        P0[k] = tab4[b4 + (i00 >> 1)];       // covers t00 (+t10 if u0 even)
        P1[k] = tab4[b4 + (i01 >> 1)];       // covers t01 (+t11 if u0 even)
        Q0[k] = make_float2(0.f, 0.f);
        Q1[k] = make_float2(0.f, 0.f);
        if (oddm[k]) {                       // exec-masked, ~50% lanes
            Q0[k] = tab[base + i10];
            Q1[k] = tab[base + i11];
        }
    }
#pragma unroll
    for (int k = 0; k < 4; ++k) {
        const uint32_t pt = pt0 + (uint32_t)k * 256u;
        const float2 lo0 = make_float2(P0[k].x, P0[k].y);
        const float2 hi0 = make_float2(P0[k].z, P0[k].w);
        const float2 lo1 = make_float2(P1[k].x, P1[k].y);
        const float2 hi1 = make_float2(P1[k].z, P1[k].w);
        const float2 t00 = sel0[k] ? hi0 : lo0;
        const float2 t01 = sel1[k] ? hi1 : lo1;
        const float2 t10 = oddm[k] ? Q0[k] : (sel0[k] ? lo0 : hi0);
        const float2 t11 = oddm[k] ? Q1[k] : (sel1[k] ? lo1 : hi1);
        const float w00 = (1.f - r0[k]) * (1.f - r1[k]);
        const float w01 = (1.f - r0[k]) * r1[k];
        const float w10 = r0[k] * (1.f - r1[k]);
        const float w11 = r0[k] * r1[k];
        ws[(size_t)gabs * NPTS + pt] = make_float2(
            w00 * t00.x + w01 * t01.x + w10 * t10.x + w11 * t11.x,
            w00 * t00.y + w01 * t01.y + w10 * t10.y + w11 * t11.y);
    }
}

// ---------------- K2: combine 3 planes, transpose via LDS -------------------
__global__ __launch_bounds__(256) void kplane_combine(
    const float2* __restrict__ ws,    // (48, NPTS)
    float2* __restrict__ out)         // (NPTS, 16)
{
    __shared__ float2 tile[16][65];
    const uint32_t pt0 = blockIdx.x * 64u;
    const uint32_t t   = threadIdx.x;
    const uint32_t lr  = t >> 6;
    const uint32_t ptl = t & 63u;

#pragma unroll
    for (int k = 0; k < 4; ++k) {
        const uint32_t lvl = (uint32_t)k * 4u + lr;
        const float2 a = ws[( 0u + lvl) * NPTS + pt0 + ptl];
        const float2 b = ws[(16u + lvl) * NPTS + pt0 + ptl];
        const float2 c = ws[(32u + lvl) * NPTS + pt0 + ptl];
        tile[lvl][ptl] = make_float2(a.x * b.x * c.x, a.y * b.y * c.y);
    }
    __syncthreads();
#pragma unroll
    for (int k = 0; k < 4; ++k) {
        const uint32_t e      = t + (uint32_t)k * 256u;
        const uint32_t out_lv = e & 15u;
        const uint32_t out_pt = e >> 4;
        out[(pt0 + out_pt) * 16u + out_lv] = tile[out_lv][out_pt];
    }
}

// ---------------- Plan B fallback: r2 3-pass + transpose --------------------
template <int P, bool FIRST>
__global__ __launch_bounds__(256) void kplane_pass(
    const float* __restrict__ pts,
    const float2* __restrict__ tab,
    float2* __restrict__ ws)
{
    const uint32_t b     = blockIdx.x;
    const uint32_t xcd   = b & 7u;
    const uint32_t s     = b >> 3;
    const uint32_t gi    = s >> 11;
    const uint32_t chunk = s & 2047u;
    const uint32_t lvl   = gi * 8u + xcd;
    const uint32_t pt    = chunk * 256u + threadIdx.x;

    constexpr int c0 = (P == 2) ? 1 : 0;
    constexpr int c1 = (P == 0) ? 1 : 2;

    const float a0  = pts[pt * 3u + c0];
    const float a1  = pts[pt * 3u + c1];
    const float res = c_res[lvl];

    const float s0 = a0 * res;
    const float s1 = a1 * res;
    const float f0 = floorf(s0);
    const float f1 = floorf(s1);
    const float r0 = s0 - f0;
    const float r1 = s1 - f1;
    const uint32_t u0 = (uint32_t)f0;
    const uint32_t hy0  = (uint32_t)f1 * PRIME1;
    const uint32_t hy1  = hy0 + PRIME1;
    const uint32_t base = ((uint32_t)P * 16u + lvl) * TSIZE;

    const float2 t00 = tab[base + (( u0       ^ hy0) & TMASK)];
    const float2 t01 = tab[base + (( u0       ^ hy1) & TMASK)];
    const float2 t10 = tab[base + (((u0 + 1u) ^ hy0) & TMASK)];
    const float2 t11 = tab[base + (((u0 + 1u) ^ hy1) & TMASK)];

    const float w00 = (1.f - r0) * (1.f - r1);
    const float w01 = (1.f - r0) * r1;
    const float w10 = r0 * (1.f - r1);
    const float w11 = r0 * r1;

    const float e0 = w00 * t00.x + w01 * t01.x + w10 * t10.x + w11 * t11.x;
    const float e1 = w00 * t00.y + w01 * t01.y + w10 * t10.y + w11 * t11.y;

    const uint32_t widx = lvl * NPTS + pt;
    if (FIRST) {
        ws[widx] = make_float2(e0, e1);
    } else {
        const float2 prev = ws[widx];
        ws[widx] = make_float2(prev.x * e0, prev.y * e1);
    }
}

__global__ __launch_bounds__(256) void kplane_transpose(
    const float2* __restrict__ ws, float2* __restrict__ out)
{
    const uint32_t tid = blockIdx.x * 256u + threadIdx.x;
    const uint32_t lvl = tid & 15u;
    const uint32_t pt  = tid >> 4;
    out[tid] = ws[lvl * NPTS + pt];
}

__global__ __launch_bounds__(256) void kplane_mono(
    const float* __restrict__ pts,
    const float2* __restrict__ tab,
    float2* __restrict__ out)
{
    const uint32_t tid = blockIdx.x * 256u + threadIdx.x;
    const uint32_t pt  = tid >> 4;
    const uint32_t lvl = tid & 15u;
    const float x = pts[pt * 3u + 0u];
    const float y = pts[pt * 3u + 1u];
    const float z = pts[pt * 3u + 2u];
    const float res = c_res[lvl];
    const float a0[3] = {x, x, y};
    const float a1[3] = {y, z, z};
    float p0 = 1.f, p1 = 1.f;
#pragma unroll
    for (int pl = 0; pl < 3; ++pl) {
        const float s0 = a0[pl] * res;
        const float s1 = a1[pl] * res;
        const float f0 = floorf(s0);
        const float f1 = floorf(s1);
        const float r0 = s0 - f0;
        const float r1 = s1 - f1;
        const uint32_t u0 = (uint32_t)f0;
        const uint32_t hy0 = (uint32_t)f1 * PRIME1;
        const uint32_t hy1 = hy0 + PRIME1;
        const uint32_t base = ((uint32_t)pl * 16u + lvl) * TSIZE;
        const float2 t00 = tab[base + (( u0       ^ hy0) & TMASK)];
        const float2 t01 = tab[base + (( u0       ^ hy1) & TMASK)];
        const float2 t10 = tab[base + (((u0 + 1u) ^ hy0) & TMASK)];
        const float2 t11 = tab[base + (((u0 + 1u) ^ hy1) & TMASK)];
        const float w00 = (1.f - r0) * (1.f - r1);
        const float w01 = (1.f - r0) * r1;
        const float w10 = r0 * (1.f - r1);
        const float w11 = r0 * r1;
        p0 *= w00 * t00.x + w01 * t01.x + w10 * t10.x + w11 * t11.x;
        p1 *= w00 * t00.y + w01 * t01.y + w10 * t10.y + w11 * t11.y;
    }
    out[pt * 16u + lvl] = make_float2(p0, p1);
}

extern "C" void kernel_launch(void* const* d_in, const int* in_sizes, int n_in,
                              void* d_out, int out_size, void* d_ws, size_t ws_size,
                              hipStream_t stream) {
    const float*  pts = (const float*)d_in[0];
    const float2* tab = (const float2*)d_in[1];
    float2*       out = (float2*)d_out;

    const size_t wsA = (size_t)48 * NPTS * sizeof(float2);   // 201.3 MB
    const size_t wsB = (size_t)16 * NPTS * sizeof(float2);   //  67.1 MB
    dim3 block256(256u);

    if (ws_size >= wsA) {
        float2* ws  = (float2*)d_ws;
        float2* scr = (float2*)d_out;   // 13.8 MB scratch, dead before combine
        hipLaunchKernelGGL(kplane_packexpand, dim3(2048u + 586u), block256,
                           0, stream, pts, tab, scr);
        hipLaunchKernelGGL(kplane_fused, dim3(1440u + 12288u), block256,
                           0, stream, scr, tab, ws);
        hipLaunchKernelGGL(kplane_combine, dim3(NPTS / 64u), block256, 0,
                           stream, ws, out);
    } else if (ws_size >= wsB) {
        float2* ws = (float2*)d_ws;
        dim3 grid(16u * (NPTS / 256u));
        hipLaunchKernelGGL((kplane_pass<0, true >), grid, block256, 0, stream, pts, tab, ws);
        hipLaunchKernelGGL((kplane_pass<1, false>), grid, block256, 0, stream, pts, tab, ws);
        hipLaunchKernelGGL((kplane_pass<2, false>), grid, block256, 0, stream, pts, tab, ws);
        dim3 tgrid((NPTS * 16u) / 256u);
        hipLaunchKernelGGL(kplane_transpose, tgrid, block256, 0, stream, ws, out);
    } else {
        dim3 grid((NPTS * 16u) / 256u);
        hipLaunchKernelGGL(kplane_mono, grid, block256, 0, stream, pts, tab, out);
    }
}

// Round 9
// 252.400 us; speedup vs baseline: 1.4041x; 1.0485x over previous
//
#include <hip/hip_runtime.h>
#include <stdint.h>

// K-Planes hash-grid encoder, MI355X.  Round 9.
// Request ledger (r1-r8): XCD-pinned divergent gathers ~4.6us/M requests.
// Structure: bucket-sort points by 16x16 cell per plane -> levels 0-11 done
// entirely in LDS per bucket (32KB rect footprint, zero overscan, scatter
// results by orig index) -> hi gather only levels 12-15 (18.9M reqs ~90us).
//  K0 pack: pts2[plane][pt] + zero hist        (d_out scratch)
//  K1 hist / K2 scan / K3 scatter: 768-bucket counting sort (atomic order
//     does not affect output values -> deterministic)
//  K4 low: per (plane,bucket) block, stage 12 level-rects (<=3961e, 32KB)
//     from hash (divergent, ~3M reqs once), interp l0-11, write 96B rows
//     ws2[orig][plane][0..11]
//  K5 hi: levels 12-15 (12 groups), XCD-pinned (8 full + 4 split jobs),
//     float4 even-u0 corner pairing, 4 pts/thread (r6-proven body)
//  K6 combine: ws2 + wsH -> out, fully coalesced
// Fallbacks: Plan B (r2 3-pass + transpose), mono.

#define NPTS   524288u
#define TSIZE  524288u
#define TMASK  0x7FFFFu
#define PRIME1 2654435761u

__constant__ float c_res[16] = {
    16.f, 22.f, 30.f, 42.f, 58.f, 80.f, 111.f, 153.f,
    212.f, 294.f, 406.f, 561.f, 775.f, 1072.f, 1481.f, 2047.f
};
__constant__ int c_resiLow[12] = {16, 22, 30, 42, 58, 80, 111, 153, 212, 294, 406, 561};

// ---------------- K0: pack per-plane coords + zero hist ---------------------
__global__ __launch_bounds__(256) void k_pack(
    const float* __restrict__ pts, float2* __restrict__ pts2,
    uint32_t* __restrict__ hist)
{
    const uint32_t b = blockIdx.x, t = threadIdx.x;
    if (b == 2048u) {                        // zero hist[768]
        if (t < 256u) { hist[t] = 0u; hist[256u + t] = 0u; hist[512u + t] = 0u; }
        return;
    }
    const uint32_t pt = b * 256u + t;
    const float x = pts[pt * 3u + 0u];
    const float y = pts[pt * 3u + 1u];
    const float z = pts[pt * 3u + 2u];
    pts2[            pt] = make_float2(x, y);
    pts2[NPTS      + pt] = make_float2(x, z);
    pts2[2u * NPTS + pt] = make_float2(y, z);
}

// ---------------- K1: per-plane 256-bucket histogram -------------------------
__global__ __launch_bounds__(256) void k_hist(
    const float2* __restrict__ pts2, uint32_t* __restrict__ hist)
{
    __shared__ uint32_t lh[256];
    const uint32_t b = blockIdx.x, t = threadIdx.x;
    const uint32_t plane = b >> 6, chunk = b & 63u;
    lh[t] = 0u;
    __syncthreads();
    const float2* __restrict__ pp = pts2 + (size_t)plane * NPTS;
    const uint32_t pt0 = chunk * 8192u + t;
    for (uint32_t k = 0; k < 32u; ++k) {
        const float2 c = pp[pt0 + k * 256u];
        const uint32_t bx = min(15u, (uint32_t)(c.x * 16.f));
        const uint32_t by = min(15u, (uint32_t)(c.y * 16.f));
        atomicAdd(&lh[bx * 16u + by], 1u);
    }
    __syncthreads();
    atomicAdd(&hist[plane * 256u + t], lh[t]);
}

// ---------------- K2: exclusive scan -> base, cursor -------------------------
__global__ __launch_bounds__(256) void k_scan(
    const uint32_t* __restrict__ hist,
    uint32_t* __restrict__ base, uint32_t* __restrict__ cursor)
{
    __shared__ uint32_t su[256];
    const uint32_t t = threadIdx.x;
    for (uint32_t p = 0; p < 3u; ++p) {
        const uint32_t h = hist[p * 256u + t];
        su[t] = h;
        __syncthreads();
        for (uint32_t off = 1u; off < 256u; off <<= 1) {
            uint32_t v = 0u;
            if (t >= off) v = su[t - off];
            __syncthreads();
            su[t] += v;
            __syncthreads();
        }
        const uint32_t ex = su[t] - h;
        base[p * 256u + t] = ex;
        cursor[p * 256u + t] = ex;
        __syncthreads();
    }
}

// ---------------- K3: scatter into bucket order ------------------------------
__global__ __launch_bounds__(256) void k_scatter(
    const float2* __restrict__ pts2, uint32_t* __restrict__ cursor,
    float4* __restrict__ sort16)
{
    __shared__ uint32_t lcnt[256], gb[256], lc2[256];
    const uint32_t b = blockIdx.x, t = threadIdx.x;
    const uint32_t plane = b >> 6, chunk = b & 63u;
    lcnt[t] = 0u; lc2[t] = 0u;
    __syncthreads();
    const float2* __restrict__ pp = pts2 + (size_t)plane * NPTS;
    const uint32_t pt0 = chunk * 8192u + t;
    for (uint32_t k = 0; k < 32u; ++k) {
        const float2 c = pp[pt0 + k * 256u];
        const uint32_t bb = min(15u, (uint32_t)(c.x * 16.f)) * 16u
                          + min(15u, (uint32_t)(c.y * 16.f));
        atomicAdd(&lcnt[bb], 1u);
    }
    __syncthreads();
    gb[t] = atomicAdd(&cursor[plane * 256u + t], lcnt[t]);
    __syncthreads();
    float4* __restrict__ sp = sort16 + (size_t)plane * NPTS;
    for (uint32_t k = 0; k < 32u; ++k) {
        const uint32_t pt = pt0 + k * 256u;
        const float2 c = pp[pt];
        const uint32_t bb = min(15u, (uint32_t)(c.x * 16.f)) * 16u
                          + min(15u, (uint32_t)(c.y * 16.f));
        const uint32_t r = atomicAdd(&lc2[bb], 1u);
        sp[gb[bb] + r] = make_float4(c.x, c.y, __uint_as_float(pt), 0.f);
    }
}

// ---------------- K4: levels 0-11 in LDS per bucket ---------------------------
__global__ __launch_bounds__(256) void k_low(
    const float2* __restrict__ tab, const float4* __restrict__ sort16,
    const uint32_t* __restrict__ hist, const uint32_t* __restrict__ base,
    float2* __restrict__ ws2)
{
    __shared__ float2 sm[4000];              // worst-case sum 3961 entries
    __shared__ uint32_t Poff[12], Pu0[12], Pu1[12], Pcols[12], Prows[12];
    const uint32_t b = blockIdx.x, t = threadIdx.x;
    const uint32_t plane = b >> 8, bucket = b & 255u;
    const uint32_t bx = bucket >> 4, by = bucket & 15u;

    if (t == 0u) {
        uint32_t off = 0u;
        for (uint32_t l = 0; l < 12u; ++l) {
            const int R = c_resiLow[l];
            const int u0s = max(0, (int)(((int)bx * R) >> 4) - 1);
            const int u0e = min(R, (int)((((int)bx + 1) * R) >> 4) + 2);
            const int u1s = max(0, (int)(((int)by * R) >> 4) - 1);
            const int u1e = min(R, (int)((((int)by + 1) * R) >> 4) + 2);
            const uint32_t rows = (uint32_t)(u0e - u0s + 1);
            const uint32_t cols = (uint32_t)(u1e - u1s + 1);
            Poff[l] = off; Pu0[l] = (uint32_t)u0s; Pu1[l] = (uint32_t)u1s;
            Pcols[l] = cols; Prows[l] = rows;
            off += rows * cols;
        }
    }
    __syncthreads();

    for (uint32_t l = 0; l < 12u; ++l) {     // divergent hash staging
        const uint32_t E = Prows[l] * Pcols[l];
        const uint32_t cols = Pcols[l], u0s = Pu0[l], u1s = Pu1[l];
        const uint32_t tb = (plane * 16u + l) * TSIZE;
        for (uint32_t i = t; i < E; i += 256u) {
            const uint32_t cx = u0s + i / cols;
            const uint32_t cy = u1s + i - (i / cols) * cols;
            sm[Poff[l] + i] = tab[tb + ((cx ^ (cy * PRIME1)) & TMASK)];
        }
    }
    __syncthreads();

    const uint32_t count = hist[plane * 256u + bucket];
    const uint32_t start = base[plane * 256u + bucket];
    const float4* __restrict__ sp = sort16 + (size_t)plane * NPTS;
    float4* __restrict__ w4 = (float4*)ws2;

    for (uint32_t i = t; i < count; i += 256u) {
        const float4 f = sp[start + i];
        const float c0 = f.x, c1 = f.y;
        const uint32_t orig = __float_as_uint(f.z);
        float2 acc[12];
#pragma unroll
        for (int l = 0; l < 12; ++l) {
            const float res = c_res[l];
            const float s0 = c0 * res;
            const float s1 = c1 * res;
            const float f0 = floorf(s0);
            const float f1 = floorf(s1);
            const float r0 = s0 - f0;        // exact f32 match to reference
            const float r1 = s1 - f1;
            const uint32_t u0 = (uint32_t)f0, u1 = (uint32_t)f1;
            const uint32_t ci = Poff[l] + (u0 - Pu0[l]) * Pcols[l] + (u1 - Pu1[l]);
            const float2 q00 = sm[ci];
            const float2 q01 = sm[ci + 1u];
            const float2 q10 = sm[ci + Pcols[l]];
            const float2 q11 = sm[ci + Pcols[l] + 1u];
            const float w00 = (1.f - r0) * (1.f - r1);
            const float w01 = (1.f - r0) * r1;
            const float w10 = r0 * (1.f - r1);
            const float w11 = r0 * r1;
            acc[l] = make_float2(
                w00 * q00.x + w01 * q01.x + w10 * q10.x + w11 * q11.x,
                w00 * q00.y + w01 * q01.y + w10 * q10.y + w11 * q11.y);
        }
        const size_t d = (size_t)orig * 18u + (size_t)plane * 6u;
        w4[d + 0] = make_float4(acc[0].x, acc[0].y, acc[1].x, acc[1].y);
        w4[d + 1] = make_float4(acc[2].x, acc[2].y, acc[3].x, acc[3].y);
        w4[d + 2] = make_float4(acc[4].x, acc[4].y, acc[5].x, acc[5].y);
        w4[d + 3] = make_float4(acc[6].x, acc[6].y, acc[7].x, acc[7].y);
        w4[d + 4] = make_float4(acc[8].x, acc[8].y, acc[9].x, acc[9].y);
        w4[d + 5] = make_float4(acc[10].x, acc[10].y, acc[11].x, acc[11].y);
    }
}

// ---------------- K5: levels 12-15 direct gather, XCD-pinned ------------------
__global__ __launch_bounds__(256) void k_hi(
    const float2* __restrict__ pts2, const float2* __restrict__ tab,
    float2* __restrict__ wsH)
{
    const uint32_t b = blockIdx.x, t = threadIdx.x;
    const uint32_t xcd = b & 7u;
    const uint32_t s   = b >> 3;             // 0..767
    uint32_t g, chunk;
    if (s < 512u) { g = xcd; chunk = s; }                      // groups 0-7 full
    else { g = 8u + (xcd >> 1); chunk = ((xcd & 1u) << 8) + (s - 512u); }
    const uint32_t plane = g % 3u;
    const uint32_t lvl   = 12u + g / 3u;
    const uint32_t gabs  = plane * 16u + lvl;
    const float    res   = c_res[lvl];
    const uint32_t tb    = gabs * TSIZE;
    const float4* __restrict__ tab4 = (const float4*)tab;
    const uint32_t b4    = gabs * (TSIZE / 2u);
    const float2* __restrict__ pp = pts2 + (size_t)plane * NPTS;
    const uint32_t pt0   = chunk * 1024u + t;

    float4 P0[4], P1[4];
    float2 Q0[4], Q1[4];
    float  r0[4], r1[4];
    uint32_t sel0[4], sel1[4], oddm[4];

#pragma unroll
    for (int k = 0; k < 4; ++k) {            // issue all loads first
        const uint32_t pt = pt0 + (uint32_t)k * 256u;
        const float2 c2 = pp[pt];
        const float s0 = c2.x * res;
        const float s1 = c2.y * res;
        const float f0 = floorf(s0);
        const float f1 = floorf(s1);
        r0[k] = s0 - f0;                     // exact f32 match to reference
        r1[k] = s1 - f1;
        const uint32_t u0  = (uint32_t)f0;
        const uint32_t hy0 = (uint32_t)f1 * PRIME1;
        const uint32_t hy1 = hy0 + PRIME1;
        const uint32_t i00 = ( u0        ^ hy0) & TMASK;
        const uint32_t i01 = ( u0        ^ hy1) & TMASK;
        const uint32_t i10 = ((u0 + 1u)  ^ hy0) & TMASK;
        const uint32_t i11 = ((u0 + 1u)  ^ hy1) & TMASK;
        sel0[k] = i00 & 1u;
        sel1[k] = i01 & 1u;
        oddm[k] = u0 & 1u;
        P0[k] = tab4[b4 + (i00 >> 1)];       // covers t00 (+t10 if u0 even)
        P1[k] = tab4[b4 + (i01 >> 1)];       // covers t01 (+t11 if u0 even)
        Q0[k] = make_float2(0.f, 0.f);
        Q1[k] = make_float2(0.f, 0.f);
        if (oddm[k]) {                       // exec-masked, ~50% lanes
            Q0[k] = tab[tb + i10];
            Q1[k] = tab[tb + i11];
        }
    }
#pragma unroll
    for (int k = 0; k < 4; ++k) {
        const uint32_t pt = pt0 + (uint32_t)k * 256u;
        const float2 lo0 = make_float2(P0[k].x, P0[k].y);
        const float2 hi0 = make_float2(P0[k].z, P0[k].w);
        const float2 lo1 = make_float2(P1[k].x, P1[k].y);
        const float2 hi1 = make_float2(P1[k].z, P1[k].w);
        const float2 t00 = sel0[k] ? hi0 : lo0;
        const float2 t01 = sel1[k] ? hi1 : lo1;
        const float2 t10 = oddm[k] ? Q0[k] : (sel0[k] ? lo0 : hi0);
        const float2 t11 = oddm[k] ? Q1[k] : (sel1[k] ? lo1 : hi1);
        const float w00 = (1.f - r0[k]) * (1.f - r1[k]);
        const float w01 = (1.f - r0[k]) * r1[k];
        const float w10 = r0[k] * (1.f - r1[k]);
        const float w11 = r0[k] * r1[k];
        wsH[(size_t)g * NPTS + pt] = make_float2(
            w00 * t00.x + w01 * t01.x + w10 * t10.x + w11 * t11.x,
            w00 * t00.y + w01 * t01.y + w10 * t10.y + w11 * t11.y);
    }
}

// ---------------- K6: combine -> out (fully coalesced) ------------------------
__global__ __launch_bounds__(256) void k_comb(
    const float2* __restrict__ ws2, const float2* __restrict__ wsH,
    float2* __restrict__ out)
{
    __shared__ float2 s2[2304];              // 64 pts x 36
    __shared__ float2 sh[768];               // 12 groups x 64 pts
    const uint32_t b = blockIdx.x, t = threadIdx.x;
    const uint32_t pt0 = b * 64u;
    const float2* __restrict__ src = ws2 + (size_t)pt0 * 36u;
    for (uint32_t i = t; i < 2304u; i += 256u) s2[i] = src[i];
    for (uint32_t i = t; i < 768u; i += 256u) {
        const uint32_t j = i >> 6, p = i & 63u;
        sh[i] = wsH[(size_t)j * NPTS + pt0 + p];
    }
    __syncthreads();
#pragma unroll
    for (uint32_t k = 0; k < 4u; ++k) {
        const uint32_t e = t + k * 256u;
        const uint32_t pt = e >> 4, l = e & 15u;
        float2 v;
        if (l < 12u) {
            const float2 a = s2[pt * 36u + l];
            const float2 bb = s2[pt * 36u + 12u + l];
            const float2 c = s2[pt * 36u + 24u + l];
            v = make_float2(a.x * bb.x * c.x, a.y * bb.y * c.y);
        } else {
            const uint32_t j0 = (l - 12u) * 3u;
            const float2 a = sh[j0 * 64u + pt];
            const float2 bb = sh[(j0 + 1u) * 64u + pt];
            const float2 c = sh[(j0 + 2u) * 64u + pt];
            v = make_float2(a.x * bb.x * c.x, a.y * bb.y * c.y);
        }
        out[(size_t)(pt0 + pt) * 16u + l] = v;
    }
}

// ---------------- Plan B fallback: r2 3-pass + transpose ---------------------
template <int P, bool FIRST>
__global__ __launch_bounds__(256) void kplane_pass(
    const float* __restrict__ pts, const float2* __restrict__ tab,
    float2* __restrict__ ws)
{
    const uint32_t b     = blockIdx.x;
    const uint32_t xcd   = b & 7u;
    const uint32_t s     = b >> 3;
    const uint32_t gi    = s >> 11;
    const uint32_t chunk = s & 2047u;
    const uint32_t lvl   = gi * 8u + xcd;
    const uint32_t pt    = chunk * 256u + threadIdx.x;
    constexpr int c0 = (P == 2) ? 1 : 0;
    constexpr int c1 = (P == 0) ? 1 : 2;
    const float a0  = pts[pt * 3u + c0];
    const float a1  = pts[pt * 3u + c1];
    const float res = c_res[lvl];
    const float s0 = a0 * res;
    const float s1 = a1 * res;
    const float f0 = floorf(s0);
    const float f1 = floorf(s1);
    const float r0 = s0 - f0;
    const float r1 = s1 - f1;
    const uint32_t u0 = (uint32_t)f0;
    const uint32_t hy0  = (uint32_t)f1 * PRIME1;
    const uint32_t hy1  = hy0 + PRIME1;
    const uint32_t base = ((uint32_t)P * 16u + lvl) * TSIZE;
    const float2 t00 = tab[base + (( u0       ^ hy0) & TMASK)];
    const float2 t01 = tab[base + (( u0       ^ hy1) & TMASK)];
    const float2 t10 = tab[base + (((u0 + 1u) ^ hy0) & TMASK)];
    const float2 t11 = tab[base + (((u0 + 1u) ^ hy1) & TMASK)];
    const float w00 = (1.f - r0) * (1.f - r1);
    const float w01 = (1.f - r0) * r1;
    const float w10 = r0 * (1.f - r1);
    const float w11 = r0 * r1;
    const float e0 = w00 * t00.x + w01 * t01.x + w10 * t10.x + w11 * t11.x;
    const float e1 = w00 * t00.y + w01 * t01.y + w10 * t10.y + w11 * t11.y;
    const uint32_t widx = lvl * NPTS + pt;
    if (FIRST) {
        ws[widx] = make_float2(e0, e1);
    } else {
        const float2 prev = ws[widx];
        ws[widx] = make_float2(prev.x * e0, prev.y * e1);
    }
}

__global__ __launch_bounds__(256) void kplane_transpose(
    const float2* __restrict__ ws, float2* __restrict__ out)
{
    const uint32_t tid = blockIdx.x * 256u + threadIdx.x;
    const uint32_t lvl = tid & 15u;
    const uint32_t pt  = tid >> 4;
    out[tid] = ws[lvl * NPTS + pt];
}

__global__ __launch_bounds__(256) void kplane_mono(
    const float* __restrict__ pts, const float2* __restrict__ tab,
    float2* __restrict__ out)
{
    const uint32_t tid = blockIdx.x * 256u + threadIdx.x;
    const uint32_t pt  = tid >> 4;
    const uint32_t lvl = tid & 15u;
    const float x = pts[pt * 3u + 0u];
    const float y = pts[pt * 3u + 1u];
    const float z = pts[pt * 3u + 2u];
    const float res = c_res[lvl];
    const float a0[3] = {x, x, y};
    const float a1[3] = {y, z, z};
    float p0 = 1.f, p1 = 1.f;
#pragma unroll
    for (int pl = 0; pl < 3; ++pl) {
        const float s0 = a0[pl] * res;
        const float s1 = a1[pl] * res;
        const float f0 = floorf(s0);
        const float f1 = floorf(s1);
        const float r0 = s0 - f0;
        const float r1 = s1 - f1;
        const uint32_t u0 = (uint32_t)f0;
        const uint32_t hy0 = (uint32_t)f1 * PRIME1;
        const uint32_t hy1 = hy0 + PRIME1;
        const uint32_t base = ((uint32_t)pl * 16u + lvl) * TSIZE;
        const float2 t00 = tab[base + (( u0       ^ hy0) & TMASK)];
        const float2 t01 = tab[base + (( u0       ^ hy1) & TMASK)];
        const float2 t10 = tab[base + (((u0 + 1u) ^ hy0) & TMASK)];
        const float2 t11 = tab[base + (((u0 + 1u) ^ hy1) & TMASK)];
        const float w00 = (1.f - r0) * (1.f - r1);
        const float w01 = (1.f - r0) * r1;
        const float w10 = r0 * (1.f - r1);
        const float w11 = r0 * r1;
        p0 *= w00 * t00.x + w01 * t01.x + w10 * t10.x + w11 * t11.x;
        p1 *= w00 * t00.y + w01 * t01.y + w10 * t10.y + w11 * t11.y;
    }
    out[pt * 16u + lvl] = make_float2(p0, p1);
}

extern "C" void kernel_launch(void* const* d_in, const int* in_sizes, int n_in,
                              void* d_out, int out_size, void* d_ws, size_t ws_size,
                              hipStream_t stream) {
    const float*  pts = (const float*)d_in[0];
    const float2* tab = (const float2*)d_in[1];
    float2*       out = (float2*)d_out;

    const size_t wsA = (size_t)48 * NPTS * sizeof(float2);   // 201.3 MB
    const size_t wsB = (size_t)16 * NPTS * sizeof(float2);   //  67.1 MB
    dim3 block256(256u);

    if (ws_size >= wsA) {
        // d_out scratch: pts2 (12.6MB) | sort16 (25.2MB) | hist/base/cursor
        float2*   pts2   = (float2*)d_out;
        float4*   sort16 = (float4*)((char*)d_out + (size_t)3 * NPTS * 8u);
        uint32_t* hist   = (uint32_t*)((char*)d_out + (size_t)3 * NPTS * 24u);
        uint32_t* bse    = hist + 768;
        uint32_t* cursor = hist + 1536;
        // d_ws: ws2 [pt][plane][12] (151MB) | wsH [12][NPTS] (50.3MB)
        float2* ws2 = (float2*)d_ws;
        float2* wsH = ws2 + (size_t)36 * NPTS;

        hipLaunchKernelGGL(k_pack,    dim3(2049u), block256, 0, stream, pts, pts2, hist);
        hipLaunchKernelGGL(k_hist,    dim3(192u),  block256, 0, stream, pts2, hist);
        hipLaunchKernelGGL(k_scan,    dim3(1u),    block256, 0, stream, hist, bse, cursor);
        hipLaunchKernelGGL(k_scatter, dim3(192u),  block256, 0, stream, pts2, cursor, sort16);
        hipLaunchKernelGGL(k_low,     dim3(768u),  block256, 0, stream, tab, sort16, hist, bse, ws2);
        hipLaunchKernelGGL(k_hi,      dim3(6144u), block256, 0, stream, pts2, tab, wsH);
        hipLaunchKernelGGL(k_comb,    dim3(NPTS / 64u), block256, 0, stream, ws2, wsH, out);
    } else if (ws_size >= wsB) {
        float2* ws = (float2*)d_ws;
        dim3 grid(16u * (NPTS / 256u));
        hipLaunchKernelGGL((kplane_pass<0, true >), grid, block256, 0, stream, pts, tab, ws);
        hipLaunchKernelGGL((kplane_pass<1, false>), grid, block256, 0, stream, pts, tab, ws);
        hipLaunchKernelGGL((kplane_pass<2, false>), grid, block256, 0, stream, pts, tab, ws);
        dim3 tgrid((NPTS * 16u) / 256u);
        hipLaunchKernelGGL(kplane_transpose, tgrid, block256, 0, stream, ws, out);
    } else {
        dim3 grid((NPTS * 16u) / 256u);
        hipLaunchKernelGGL(kplane_mono, grid, block256, 0, stream, pts, tab, out);
    }
}